// Round 1
// 559.895 us; speedup vs baseline: 1.0940x; 1.0940x over previous
//
#include <hip/hip_runtime.h>
#include <hip/hip_bf16.h>
#include <math.h>

// Inputs fp32; output fp32. GEMM math: bf16 MFMA, fp32 accumulate.
// R4 changes vs 612us baseline:
//   1. global_load_lds(16B) staging in both GEMMs (m97 structure; was VALU-bound
//      reg-staging: MfmaUtil 22 / VALUBusy 38).
//   2. XCD-aware bijective block swizzle (T1) — FETCH was 397MB vs ~103MB ideal.
//   3. attn GEMM retiled 128x128 -> 64x64 (64 -> 256 workgroups; was 25% CU use).
typedef __attribute__((ext_vector_type(8))) short  short8;   // 8 bf16 (16 B)
typedef __attribute__((ext_vector_type(4))) float  floatx4;  // MFMA C/D frag

__device__ __forceinline__ ushort f2bf(float f) {
    __hip_bfloat16 hb = __float2bfloat16(f);  // round-to-nearest-even
    return *(ushort*)&hb;
}
__device__ __forceinline__ short8 pack8(float4 a, float4 b) {
    union { short8 v; ushort u[8]; } r;
    r.u[0] = f2bf(a.x); r.u[1] = f2bf(a.y); r.u[2] = f2bf(a.z); r.u[3] = f2bf(a.w);
    r.u[4] = f2bf(b.x); r.u[5] = f2bf(b.y); r.u[6] = f2bf(b.z); r.u[7] = f2bf(b.w);
    return r.v;
}

// async global->LDS, 16 B per lane. LDS dest must be wave-uniform (base + lane*16).
typedef __attribute__((address_space(1))) const void* gas1_t;
typedef __attribute__((address_space(3))) void*       las3_t;
__device__ __forceinline__ void gload16(const void* g, void* l) {
    __builtin_amdgcn_global_load_lds((gas1_t)g, (las3_t)l, 16, 0, 0);
}

// ---------------------------------------------------------------------------
// fp32 -> bf16 bulk convert. n8 = elements/8 (exact multiples here).
__global__ __launch_bounds__(256) void k_cvt(const float* __restrict__ in,
                                             ushort* __restrict__ out, int n8) {
    int i = blockIdx.x * 256 + threadIdx.x;
    if (i >= n8) return;
    const float4* p = reinterpret_cast<const float4*>(in) + (size_t)i * 2;
    float4 a = p[0], b = p[1];
    *reinterpret_cast<short8*>(out + (size_t)i * 8) = pack8(a, b);
}

// ---------------------------------------------------------------------------
// fc1_w fp32 [4096 d][1024 s] -> fc1T bf16 [1024 s][4096 d]. 64x64 tiles.
__global__ __launch_bounds__(256) void k_transpose(const float* __restrict__ in,
                                                   ushort* __restrict__ out) {
    __shared__ float sm[64][65];
    const int tid = threadIdx.x;
    const int s0 = blockIdx.x * 64;   // input col tile (s)
    const int d0 = blockIdx.y * 64;   // input row tile (d)
#pragma unroll
    for (int i = 0; i < 4; ++i) {
        int lin = i * 256 + tid;
        int dr  = lin >> 4;          // 0..63
        int sc4 = lin & 15;          // 0..15 (float4 of s)
        float4 v = *reinterpret_cast<const float4*>(&in[(size_t)(d0 + dr) * 1024 + s0 + sc4 * 4]);
        sm[dr][sc4 * 4 + 0] = v.x; sm[dr][sc4 * 4 + 1] = v.y;
        sm[dr][sc4 * 4 + 2] = v.z; sm[dr][sc4 * 4 + 3] = v.w;
    }
    __syncthreads();
#pragma unroll
    for (int i = 0; i < 8; ++i) {
        int lin = i * 256 + tid;
        int dc2 = lin & 31;          // pairs of d (coalesced store dim)
        int sr  = lin >> 5;          // 0..63
        uint lo = (uint)f2bf(sm[dc2 * 2][sr]);
        uint hi = (uint)f2bf(sm[dc2 * 2 + 1][sr]);
        *reinterpret_cast<uint*>(&out[(size_t)(s0 + sr) * 4096 + d0 + dc2 * 2]) = lo | (hi << 16);
    }
}

// ---------------------------------------------------------------------------
// bf16 GEMM: C[m][n] = sum_k A[m][k]*B[n][k].  BK=32, 4 waves (2x2), BMxBN tile.
// Staging via global_load_lds (wave-uniform LDS base, linear layout).
// EPI=0: attn epilogue ((acc + bias[t]) * mask[s][t]) -> attnT[t][s] bf16
// EPI=1: exact-erf GELU -> C[m][n] fp32
// SWZ=1: XCD-aware bijective block swizzle (requires nwg % 8 == 0).
template <int BM, int BN, int EPI, int SWZ>
__global__ __launch_bounds__(256) void k_gemm_b(const ushort* __restrict__ A,
                                                const ushort* __restrict__ B,
                                                const float* __restrict__ bias,
                                                const float* __restrict__ mask,
                                                void* __restrict__ Cout,
                                                int lda, int ldb, int ksteps) {
    __shared__ ushort As[BM * 32];
    __shared__ ushort Bs[BN * 32];
    const int tid  = threadIdx.x;
    const int wave = tid >> 6, lane = tid & 63;
    const int wm = wave >> 1, wn = wave & 1;
    const int quad = lane >> 4, m16 = lane & 15;

    int bx = blockIdx.x, by = blockIdx.y;
    if (SWZ) {
        const int nx   = gridDim.x;
        const int nwg  = nx * gridDim.y;
        const int orig = by * nx + bx;
        const int cpx  = nwg >> 3;                 // nwg % 8 == 0 at both call sites
        const int w    = (orig & 7) * cpx + (orig >> 3);
        bx = w % nx; by = w / nx;                  // n fastest within an XCD chunk
    }
    const int n0 = bx * BN;
    const int m0 = by * BM;

    constexpr int AI = BM / 32;   // 16-row A frags per wave
    constexpr int BJ = BN / 32;
    floatx4 acc[AI][BJ];
    const floatx4 zero = {0.f, 0.f, 0.f, 0.f};
#pragma unroll
    for (int i = 0; i < AI; ++i)
#pragma unroll
        for (int j = 0; j < BJ; ++j) acc[i][j] = zero;

    // one gload16 covers 16 rows x 32 k (64 lanes x 16 B): row = base + lane/4,
    // k-chunk = (lane&3)*8. LDS dest linear => matches wave-uniform base + lane*16.
    const int gr = lane >> 2;
    const int gc = (lane & 3) * 8;

    for (int kt = 0; kt < ksteps; ++kt) {
        const int k0 = kt * 32;
        if (kt) __syncthreads();   // prior iter's LDS reads done before overwrite
#pragma unroll
        for (int t = 0; t < BM / 64; ++t) {
            const int r = wave * (BM / 4) + t * 16;
            gload16(&A[(size_t)(m0 + r + gr) * lda + k0 + gc], &As[r * 32]);
        }
#pragma unroll
        for (int t = 0; t < BN / 64; ++t) {
            const int r = wave * (BN / 4) + t * 16;
            gload16(&B[(size_t)(n0 + r + gr) * ldb + k0 + gc], &Bs[r * 32]);
        }
        __syncthreads();           // compiler drains vmcnt(0) before s_barrier

        short8 aF[AI], bF[BJ];
#pragma unroll
        for (int i = 0; i < AI; ++i)
            aF[i] = *reinterpret_cast<const short8*>(&As[(wm * (BM / 2) + i * 16 + m16) * 32 + quad * 8]);
#pragma unroll
        for (int j = 0; j < BJ; ++j)
            bF[j] = *reinterpret_cast<const short8*>(&Bs[(wn * (BN / 2) + j * 16 + m16) * 32 + quad * 8]);
#pragma unroll
        for (int i = 0; i < AI; ++i)
#pragma unroll
            for (int j = 0; j < BJ; ++j)
                acc[i][j] = __builtin_amdgcn_mfma_f32_16x16x32_bf16(aF[i], bF[j], acc[i][j], 0, 0, 0);
    }

    // C/D layout (verified m89/m91): col = lane&15, row = quad*4 + reg
#pragma unroll
    for (int i = 0; i < AI; ++i) {
#pragma unroll
        for (int j = 0; j < BJ; ++j) {
            const int col = n0 + wn * (BN / 2) + j * 16 + m16;
            float bv = 0.f;
            if (EPI == 0) bv = bias[col];
#pragma unroll
            for (int rr = 0; rr < 4; ++rr) {
                const int row = m0 + wm * (BM / 2) + i * 16 + quad * 4 + rr;
                float v = acc[i][j][rr];
                if (EPI == 0) {
                    v = (v + bv) * mask[(size_t)row * 1024 + col];
                    ((ushort*)Cout)[(size_t)col * 1024 + row] = f2bf(v);  // attnT[t][s]
                } else {
                    float g = 0.5f * v * (1.0f + erff(v * 0.70710678118654752f));
                    ((float*)Cout)[(size_t)row * 1024 + col] = g;  // fp32 out
                }
            }
        }
    }
}

// ---------------------------------------------------------------------------
// Fallback main GEMM reading fp32 A directly (only if ws can't hold xb).
__global__ __launch_bounds__(256) void k_gemm_f32a(const float* __restrict__ Af,
                                                   const ushort* __restrict__ B,
                                                   float* __restrict__ Cout,
                                                   int lda, int ldb, int ksteps) {
    __shared__ ushort As[128 * 32];
    __shared__ ushort Bs[128 * 32];
    const int tid  = threadIdx.x;
    const int wave = tid >> 6, lane = tid & 63;
    const int wm = wave >> 1, wn = wave & 1;
    const int quad = lane >> 4, m16 = lane & 15;
    const int n0 = blockIdx.x * 128;
    const int m0 = blockIdx.y * 128;

    floatx4 acc[4][4];
    const floatx4 zero = {0.f, 0.f, 0.f, 0.f};
#pragma unroll
    for (int i = 0; i < 4; ++i)
#pragma unroll
        for (int j = 0; j < 4; ++j) acc[i][j] = zero;

    const int s_r = tid >> 2;
    const int s_c = tid & 3;
    const int gr = lane >> 2;
    const int gc = (lane & 3) * 8;

    for (int kt = 0; kt < ksteps; ++kt) {
        const int k0 = kt * 32;
        const float* r0 = &Af[(size_t)(m0 + s_r) * lda + k0 + s_c * 8];
        const float* r1 = &Af[(size_t)(m0 + 64 + s_r) * lda + k0 + s_c * 8];
        short8 a0 = pack8(*reinterpret_cast<const float4*>(r0), *reinterpret_cast<const float4*>(r0 + 4));
        short8 a1 = pack8(*reinterpret_cast<const float4*>(r1), *reinterpret_cast<const float4*>(r1 + 4));
        __syncthreads();
        *reinterpret_cast<short8*>(&As[(s_r)      * 32 + s_c * 8]) = a0;
        *reinterpret_cast<short8*>(&As[(64 + s_r) * 32 + s_c * 8]) = a1;
#pragma unroll
        for (int t = 0; t < 2; ++t) {
            const int r = wave * 32 + t * 16;
            gload16(&B[(size_t)(n0 + r + gr) * ldb + k0 + gc], &Bs[r * 32]);
        }
        __syncthreads();

        short8 aF[4], bF[4];
#pragma unroll
        for (int i = 0; i < 4; ++i)
            aF[i] = *reinterpret_cast<const short8*>(&As[(wm * 64 + i * 16 + m16) * 32 + quad * 8]);
#pragma unroll
        for (int j = 0; j < 4; ++j)
            bF[j] = *reinterpret_cast<const short8*>(&Bs[(wn * 64 + j * 16 + m16) * 32 + quad * 8]);
#pragma unroll
        for (int i = 0; i < 4; ++i)
#pragma unroll
            for (int j = 0; j < 4; ++j)
                acc[i][j] = __builtin_amdgcn_mfma_f32_16x16x32_bf16(aF[i], bF[j], acc[i][j], 0, 0, 0);
    }

#pragma unroll
    for (int i = 0; i < 4; ++i)
#pragma unroll
        for (int j = 0; j < 4; ++j) {
            const int col = n0 + wn * 64 + j * 16 + m16;
#pragma unroll
            for (int rr = 0; rr < 4; ++rr) {
                const int row = m0 + wm * 64 + i * 16 + quad * 4 + rr;
                float v = acc[i][j][rr];
                Cout[(size_t)row * 1024 + col] = 0.5f * v * (1.0f + erff(v * 0.70710678118654752f));
            }
        }
}

// ---------------------------------------------------------------------------
extern "C" void kernel_launch(void* const* d_in, const int* in_sizes, int n_in,
                              void* d_out, int out_size, void* d_ws, size_t ws_size,
                              hipStream_t stream) {
    const float* x    = (const float*)d_in[0];  // [49152][1024] fp32
    const float* fc1w = (const float*)d_in[1];  // [4096][1024]  fp32
    const float* fc2w = (const float*)d_in[2];  // [1024][4096]  fp32
    const float* fc2b = (const float*)d_in[3];  // [1024]        fp32
    const float* mask = (const float*)d_in[4];  // [1024][1024]  fp32, s-major

    char* ws = (char*)d_ws;
    ushort* fc1T  = (ushort*)ws;                  //  8 MiB [1024 s][4096 d] bf16
    ushort* fc2wb = (ushort*)(ws + (8u  << 20));  //  8 MiB [1024 t][4096 d] bf16
    ushort* attnT = (ushort*)(ws + (16u << 20));  //  2 MiB [1024 t][1024 s] bf16
    ushort* xb    = (ushort*)(ws + (18u << 20));  // 96 MiB [49152][1024] bf16 (optional)
    const size_t XB_BYTES = 50331648ull * 2;
    const bool has_xb = ws_size >= (size_t)(18u << 20) + XB_BYTES;

    // weight prep (small)
    k_transpose<<<dim3(16, 64), 256, 0, stream>>>(fc1w, fc1T);
    k_cvt<<<2048, 256, 0, stream>>>(fc2w, fc2wb, 524288);
    // attn: attnT[t][s] = bf16((fc1T·fc2wb^T + bias) * mask).
    // 64x64 tiles -> 256 workgroups = full CU coverage (was 64 wg = 25%).
    k_gemm_b<64, 64, 0, 1><<<dim3(16, 16), 256, 0, stream>>>(
        fc1T, fc2wb, fc2b, mask, attnT, 4096, 4096, 128);
    // main: out[m][t] = gelu(x·attnT^T), fp32 store
    if (has_xb) {
        k_cvt<<<24576, 256, 0, stream>>>(x, xb, 6291456);
        k_gemm_b<128, 128, 1, 1><<<dim3(8, 384), 256, 0, stream>>>(
            xb, attnT, nullptr, nullptr, d_out, 1024, 1024, 32);
    } else {
        k_gemm_f32a<<<dim3(8, 384), 256, 0, stream>>>(x, attnT, (float*)d_out, 1024, 1024, 32);
    }
}

// Round 2
// 509.286 us; speedup vs baseline: 1.2027x; 1.0994x over previous
//
#include <hip/hip_runtime.h>
#include <hip/hip_bf16.h>
#include <math.h>

// R5: main GEMM rewritten as the 256x256 8-phase pipeline (T2 LDS XOR-swizzle +
// T3/T4 counted-vmcnt phases + T5 setprio). R1 showed the m97 2-barrier
// structure is stall-bound at this shape (Mfma 20 / VALU 20 / occ 30, fetch
// already ideal). attn GEMM K-split x4 (256 wg -> 1024 wg) + combine kernel.
typedef __attribute__((ext_vector_type(8))) short  short8;   // 8 bf16 (16 B)
typedef __attribute__((ext_vector_type(4))) float  floatx4;  // MFMA C/D frag
typedef __attribute__((ext_vector_type(4))) int    i32x4;

__device__ __forceinline__ ushort f2bf(float f) {
    __hip_bfloat16 hb = __float2bfloat16(f);  // round-to-nearest-even
    return *(ushort*)&hb;
}
__device__ __forceinline__ short8 pack8(float4 a, float4 b) {
    union { short8 v; ushort u[8]; } r;
    r.u[0] = f2bf(a.x); r.u[1] = f2bf(a.y); r.u[2] = f2bf(a.z); r.u[3] = f2bf(a.w);
    r.u[4] = f2bf(b.x); r.u[5] = f2bf(b.y); r.u[6] = f2bf(b.z); r.u[7] = f2bf(b.w);
    return r.v;
}

// async global->LDS, 16 B per lane. LDS dest wave-uniform base + lane*16.
typedef __attribute__((address_space(1))) const void* gas1_t;
typedef __attribute__((address_space(3))) void*       las3_t;
__device__ __forceinline__ void gload16(const void* g, void* l) {
    __builtin_amdgcn_global_load_lds((gas1_t)g, (las3_t)l, 16, 0, 0);
}
// raw ds_read_b128 at a 32-bit LDS byte address (opaque to the waitcnt pass;
// we manage lgkmcnt manually -- rule 18: lgkmcnt(0) + sched_barrier(0)).
__device__ __forceinline__ short8 ds_read16(uint off) {
    union { i32x4 i; short8 s; } u;
    asm volatile("ds_read_b128 %0, %1" : "=v"(u.i) : "v"(off));
    return u.s;
}

// ---------------------------------------------------------------------------
// fp32 -> bf16 bulk convert. n8 = elements/8 (exact multiples here).
__global__ __launch_bounds__(256) void k_cvt(const float* __restrict__ in,
                                             ushort* __restrict__ out, int n8) {
    int i = blockIdx.x * 256 + threadIdx.x;
    if (i >= n8) return;
    const float4* p = reinterpret_cast<const float4*>(in) + (size_t)i * 2;
    float4 a = p[0], b = p[1];
    *reinterpret_cast<short8*>(out + (size_t)i * 8) = pack8(a, b);
}

// ---------------------------------------------------------------------------
// fc1_w fp32 [4096 d][1024 s] -> fc1T bf16 [1024 s][4096 d]. 64x64 tiles.
__global__ __launch_bounds__(256) void k_transpose(const float* __restrict__ in,
                                                   ushort* __restrict__ out) {
    __shared__ float sm[64][65];
    const int tid = threadIdx.x;
    const int s0 = blockIdx.x * 64;
    const int d0 = blockIdx.y * 64;
#pragma unroll
    for (int i = 0; i < 4; ++i) {
        int lin = i * 256 + tid;
        int dr  = lin >> 4;
        int sc4 = lin & 15;
        float4 v = *reinterpret_cast<const float4*>(&in[(size_t)(d0 + dr) * 1024 + s0 + sc4 * 4]);
        sm[dr][sc4 * 4 + 0] = v.x; sm[dr][sc4 * 4 + 1] = v.y;
        sm[dr][sc4 * 4 + 2] = v.z; sm[dr][sc4 * 4 + 3] = v.w;
    }
    __syncthreads();
#pragma unroll
    for (int i = 0; i < 8; ++i) {
        int lin = i * 256 + tid;
        int dc2 = lin & 31;
        int sr  = lin >> 5;
        uint lo = (uint)f2bf(sm[dc2 * 2][sr]);
        uint hi = (uint)f2bf(sm[dc2 * 2 + 1][sr]);
        *reinterpret_cast<uint*>(&out[(size_t)(s0 + sr) * 4096 + d0 + dc2 * 2]) = lo | (hi << 16);
    }
}

// ---------------------------------------------------------------------------
// bf16 GEMM (m97 structure): C[m][n] = sum_k A[m][k]*B[n][k]. BK=32, 4 waves.
// EPI=0: ((acc+bias[t])*mask[s][t]) -> attnT[t][s] bf16
// EPI=1: exact-erf GELU -> C[m][n] fp32
// EPI=2: K-split partial (blockIdx.z = split of 1024 k): raw fp32 -> P[t][s]
template <int BM, int BN, int EPI, int SWZ>
__global__ __launch_bounds__(256) void k_gemm_b(const ushort* __restrict__ A,
                                                const ushort* __restrict__ B,
                                                const float* __restrict__ bias,
                                                const float* __restrict__ mask,
                                                void* __restrict__ Cout,
                                                int lda, int ldb, int ksteps) {
    __shared__ ushort As[BM * 32];
    __shared__ ushort Bs[BN * 32];
    const int tid  = threadIdx.x;
    const int wave = tid >> 6, lane = tid & 63;
    const int wm = wave >> 1, wn = wave & 1;
    const int quad = lane >> 4, m16 = lane & 15;

    if (EPI == 2) {
        const int sp = blockIdx.z;
        A += (size_t)sp * 1024;
        B += (size_t)sp * 1024;
        Cout = (void*)((float*)Cout + (size_t)sp * 1048576);
    }

    int bx = blockIdx.x, by = blockIdx.y;
    if (SWZ) {
        const int nx   = gridDim.x;
        const int nwg  = nx * gridDim.y;
        const int orig = by * nx + bx;
        const int cpx  = nwg >> 3;
        const int w    = (orig & 7) * cpx + (orig >> 3);
        bx = w % nx; by = w / nx;
    }
    const int n0 = bx * BN;
    const int m0 = by * BM;

    constexpr int AI = BM / 32;
    constexpr int BJ = BN / 32;
    floatx4 acc[AI][BJ];
    const floatx4 zero = {0.f, 0.f, 0.f, 0.f};
#pragma unroll
    for (int i = 0; i < AI; ++i)
#pragma unroll
        for (int j = 0; j < BJ; ++j) acc[i][j] = zero;

    const int gr = lane >> 2;
    const int gc = (lane & 3) * 8;

    for (int kt = 0; kt < ksteps; ++kt) {
        const int k0 = kt * 32;
        if (kt) __syncthreads();
#pragma unroll
        for (int t = 0; t < BM / 64; ++t) {
            const int r = wave * (BM / 4) + t * 16;
            gload16(&A[(size_t)(m0 + r + gr) * lda + k0 + gc], &As[r * 32]);
        }
#pragma unroll
        for (int t = 0; t < BN / 64; ++t) {
            const int r = wave * (BN / 4) + t * 16;
            gload16(&B[(size_t)(n0 + r + gr) * ldb + k0 + gc], &Bs[r * 32]);
        }
        __syncthreads();

        short8 aF[AI], bF[BJ];
#pragma unroll
        for (int i = 0; i < AI; ++i)
            aF[i] = *reinterpret_cast<const short8*>(&As[(wm * (BM / 2) + i * 16 + m16) * 32 + quad * 8]);
#pragma unroll
        for (int j = 0; j < BJ; ++j)
            bF[j] = *reinterpret_cast<const short8*>(&Bs[(wn * (BN / 2) + j * 16 + m16) * 32 + quad * 8]);
#pragma unroll
        for (int i = 0; i < AI; ++i)
#pragma unroll
            for (int j = 0; j < BJ; ++j)
                acc[i][j] = __builtin_amdgcn_mfma_f32_16x16x32_bf16(aF[i], bF[j], acc[i][j], 0, 0, 0);
    }

    // C/D layout (verified m89/m91): col = lane&15, row = quad*4 + reg
#pragma unroll
    for (int i = 0; i < AI; ++i) {
#pragma unroll
        for (int j = 0; j < BJ; ++j) {
            const int col = n0 + wn * (BN / 2) + j * 16 + m16;
            float bv = 0.f;
            if (EPI == 0) bv = bias[col];
#pragma unroll
            for (int rr = 0; rr < 4; ++rr) {
                const int row = m0 + wm * (BM / 2) + i * 16 + quad * 4 + rr;
                float v = acc[i][j][rr];
                if (EPI == 0) {
                    v = (v + bv) * mask[(size_t)row * 1024 + col];
                    ((ushort*)Cout)[(size_t)col * 1024 + row] = f2bf(v);
                } else if (EPI == 1) {
                    float g = 0.5f * v * (1.0f + erff(v * 0.70710678118654752f));
                    ((float*)Cout)[(size_t)row * 1024 + col] = g;
                } else {
                    ((float*)Cout)[(size_t)col * 1024 + row] = v;   // P[t][s] fp32
                }
            }
        }
    }
}

// ---------------------------------------------------------------------------
// attn finish: attnT[t][s] = bf16((sum_sp P[sp][t][s] + bias[t]) * mask[s][t])
__global__ __launch_bounds__(256) void k_attn_fin(const float* __restrict__ P,
                                                  const float* __restrict__ bias,
                                                  const float* __restrict__ mask,
                                                  ushort* __restrict__ attnT) {
    const int idx = blockIdx.x * 256 + threadIdx.x;   // 131072 total
    const int t  = idx >> 7;
    const int s0 = (idx & 127) << 3;
    float s[8];
#pragma unroll
    for (int j = 0; j < 8; ++j) s[j] = 0.f;
#pragma unroll
    for (int sp = 0; sp < 4; ++sp) {
        const float4* p = reinterpret_cast<const float4*>(&P[(size_t)sp * 1048576 + (size_t)t * 1024 + s0]);
        float4 a = p[0], b = p[1];
        s[0] += a.x; s[1] += a.y; s[2] += a.z; s[3] += a.w;
        s[4] += b.x; s[5] += b.y; s[6] += b.z; s[7] += b.w;
    }
    const float bv = bias[t];
    union { short8 v; ushort u[8]; } r;
#pragma unroll
    for (int j = 0; j < 8; ++j) {
        float v = (s[j] + bv) * mask[(size_t)(s0 + j) * 1024 + t];
        r.u[j] = f2bf(v);
    }
    *reinterpret_cast<short8*>(&attnT[(size_t)t * 1024 + s0]) = r.v;
}

// ---------------------------------------------------------------------------
// 8-phase 256x256 main GEMM. M=49152 N=1024 K=1024, lda=ldb=ldc=1024.
// 512 thr = 8 waves (2m x 4n), BK=64, NT=16 K-tiles, LDS 128 KiB:
// [2 buf][A 32K | B 32K], each mat [2 ksub][256 rows][32 k] (64 B rows).
// Swizzle (T2, read side): byte ^= ((row>>1)&3)<<4  -> conflict-free b128.
// Staging (linear DMA dest) pre-swizzles the GLOBAL source (rule 21).
// Half-tile stream per K-tile: (A-k0, B-k0, A-k1, B-k1); 1 HT staged/phase
// (2 gload_lds per wave); vmcnt(4) at tile boundaries (T4: never 0 mid-loop).
#define GPH(T_, C_, KS_, MH_, RDB_, NB_)                                         \
  do {                                                                           \
    _Pragma("unroll")                                                            \
    for (int i_ = 0; i_ < 4; ++i_)                                               \
      aA[i_] = ds_read16(bA_ + (uint)((KS_) * 16384 + ((MH_) * 4 + i_) * 1024)); \
    if (RDB_) {                                                                  \
      _Pragma("unroll")                                                          \
      for (int j_ = 0; j_ < 4; ++j_)                                             \
        bB[j_] = ds_read16(bB_ + (uint)((KS_) * 16384 + j_ * 1024));             \
    }                                                                            \
    stage_ht(4 * (T_) + (C_) + 5);                                               \
    __builtin_amdgcn_sched_barrier(0);                                           \
    __builtin_amdgcn_s_barrier();                                                \
    asm volatile("s_waitcnt lgkmcnt(0)");                                        \
    __builtin_amdgcn_sched_barrier(0);                                           \
    __builtin_amdgcn_s_setprio(1);                                               \
    _Pragma("unroll")                                                            \
    for (int i_ = 0; i_ < 4; ++i_) {                                             \
      _Pragma("unroll")                                                          \
      for (int j_ = 0; j_ < 4; ++j_)                                             \
        acc[(MH_) * 4 + i_][j_] = __builtin_amdgcn_mfma_f32_16x16x32_bf16(       \
            aA[i_], bB[j_], acc[(MH_) * 4 + i_][j_], 0, 0, 0);                   \
    }                                                                            \
    __builtin_amdgcn_s_setprio(0);                                               \
    __builtin_amdgcn_sched_barrier(0);                                           \
    if ((NB_) >= 0) {                                                            \
      if ((NB_) == 4) asm volatile("s_waitcnt vmcnt(4)");                        \
      else            asm volatile("s_waitcnt vmcnt(0)");                        \
      __builtin_amdgcn_sched_barrier(0);                                         \
    }                                                                            \
    __builtin_amdgcn_s_barrier();                                                \
    __builtin_amdgcn_sched_barrier(0);                                           \
  } while (0)

__global__ __launch_bounds__(512) void k_gemm8(const ushort* __restrict__ A,
                                               const ushort* __restrict__ B,
                                               float* __restrict__ C) {
    constexpr int NT = 16;
    __shared__ __align__(16) ushort lds[65536];   // 128 KiB

    const int tid  = threadIdx.x;
    const int wave = tid >> 6, lane = tid & 63;
    const int wm = wave >> 2, wn = wave & 3;
    const int quad = lane >> 4, m16 = lane & 15;

    // XCD-bijective swizzle, nwg = 768 (96/XCD), n fastest within a chunk.
    const int orig = blockIdx.y * 4 + blockIdx.x;
    const int wsz  = (orig & 7) * 96 + (orig >> 3);
    const int n0 = (wsz & 3) * 256;
    const int m0 = (wsz >> 2) * 256;

    const uint lds0 = (uint)(size_t)(las3_t)(void*)lds;
    const uint xorM = (uint)((m16 & 6) << 3);     // row bits1-2 -> byte bits4-5
    const uint baseA = lds0 + ((((uint)(wm * 128 + m16)) * 64u + (uint)quad * 16u) ^ xorM);
    const uint baseB = lds0 + 32768u + ((((uint)(wn * 64 + m16)) * 64u + (uint)quad * 16u) ^ xorM);

    // staging lane constants: subtile = 1024 B = 16 rows x 64 B; lane -> row
    // lane>>2, chunk swizzled (l&3)^((l>>3)&3)  (inverse of the read XOR).
    const int srow   = lane >> 2;
    const int schunk = (((lane & 3) ^ ((lane >> 3) & 3)) << 3);   // k-elem off

    auto stage_ht = [&](int g) {
        if (g >= 4 * NT) return;
        const int tg = g >> 2, ig = g & 3;
        const int mat = ig & 1, ks = ig >> 1;
        const int kc  = tg * 64 + ks * 32 + schunk;
        const uint dst0 = (uint)(((tg & 1) << 16) | (mat << 15) | (ks << 14));
        const ushort* src = mat ? B : A;
        const int r0 = (mat ? n0 : m0) + srow;
#pragma unroll
        for (int e = 0; e < 2; ++e) {
            const int s = e * 8 + wave;
            gload16(&src[(size_t)(r0 + s * 16) * 1024 + kc],
                    (void*)((char*)lds + dst0 + (uint)(s << 10)));
        }
    };

    floatx4 acc[8][4];
    const floatx4 zf = {0.f, 0.f, 0.f, 0.f};
#pragma unroll
    for (int i = 0; i < 8; ++i)
#pragma unroll
        for (int j = 0; j < 4; ++j) acc[i][j] = zf;
    short8 aA[4], bB[4];

    // prologue: tile0 (4 HT) + tile1's A-k0, B-k0; then tile0 guaranteed.
#pragma unroll
    for (int g = 0; g < 6; ++g) stage_ht(g);
    asm volatile("s_waitcnt vmcnt(4)");
    __builtin_amdgcn_sched_barrier(0);
    __builtin_amdgcn_s_barrier();
    __builtin_amdgcn_sched_barrier(0);

    for (int tp = 0; tp < NT / 2; ++tp) {
        const int t0 = 2 * tp, t1 = 2 * tp + 1;
        {
            const uint bA_ = baseA, bB_ = baseB;              // buf 0
            GPH(t0, 1, 0, 0, 1, -1);
            GPH(t0, 2, 0, 1, 0, -1);
            GPH(t0, 3, 1, 0, 1, -1);
            GPH(t0, 4, 1, 1, 0, (tp < 7) ? 4 : 0);
        }
        {
            const uint bA_ = baseA + 65536u, bB_ = baseB + 65536u;  // buf 1
            GPH(t1, 1, 0, 0, 1, -1);
            GPH(t1, 2, 0, 1, 0, -1);
            GPH(t1, 3, 1, 0, 1, -1);
            GPH(t1, 4, 1, 1, 0, (tp < 7) ? 4 : -1);
        }
    }

    // epilogue: exact-erf GELU, fp32 store
#pragma unroll
    for (int mf = 0; mf < 8; ++mf) {
#pragma unroll
        for (int nf = 0; nf < 4; ++nf) {
            const int col = n0 + wn * 64 + nf * 16 + m16;
#pragma unroll
            for (int rr = 0; rr < 4; ++rr) {
                const int row = m0 + wm * 128 + mf * 16 + quad * 4 + rr;
                const float v = acc[mf][nf][rr];
                C[(size_t)row * 1024 + col] = 0.5f * v * (1.0f + erff(v * 0.70710678118654752f));
            }
        }
    }
}

// ---------------------------------------------------------------------------
// Fallback main GEMM reading fp32 A directly (only if ws can't hold xb).
__global__ __launch_bounds__(256) void k_gemm_f32a(const float* __restrict__ Af,
                                                   const ushort* __restrict__ B,
                                                   float* __restrict__ Cout,
                                                   int lda, int ldb, int ksteps) {
    __shared__ ushort As[128 * 32];
    __shared__ ushort Bs[128 * 32];
    const int tid  = threadIdx.x;
    const int wave = tid >> 6, lane = tid & 63;
    const int wm = wave >> 1, wn = wave & 1;
    const int quad = lane >> 4, m16 = lane & 15;
    const int n0 = blockIdx.x * 128;
    const int m0 = blockIdx.y * 128;

    floatx4 acc[4][4];
    const floatx4 zero = {0.f, 0.f, 0.f, 0.f};
#pragma unroll
    for (int i = 0; i < 4; ++i)
#pragma unroll
        for (int j = 0; j < 4; ++j) acc[i][j] = zero;

    const int s_r = tid >> 2;
    const int s_c = tid & 3;
    const int gr = lane >> 2;
    const int gc = (lane & 3) * 8;

    for (int kt = 0; kt < ksteps; ++kt) {
        const int k0 = kt * 32;
        const float* r0 = &Af[(size_t)(m0 + s_r) * lda + k0 + s_c * 8];
        const float* r1 = &Af[(size_t)(m0 + 64 + s_r) * lda + k0 + s_c * 8];
        short8 a0 = pack8(*reinterpret_cast<const float4*>(r0), *reinterpret_cast<const float4*>(r0 + 4));
        short8 a1 = pack8(*reinterpret_cast<const float4*>(r1), *reinterpret_cast<const float4*>(r1 + 4));
        __syncthreads();
        *reinterpret_cast<short8*>(&As[(s_r)      * 32 + s_c * 8]) = a0;
        *reinterpret_cast<short8*>(&As[(64 + s_r) * 32 + s_c * 8]) = a1;
#pragma unroll
        for (int t = 0; t < 2; ++t) {
            const int r = wave * 32 + t * 16;
            gload16(&B[(size_t)(n0 + r + gr) * ldb + k0 + gc], &Bs[r * 32]);
        }
        __syncthreads();

        short8 aF[4], bF[4];
#pragma unroll
        for (int i = 0; i < 4; ++i)
            aF[i] = *reinterpret_cast<const short8*>(&As[(wm * 64 + i * 16 + m16) * 32 + quad * 8]);
#pragma unroll
        for (int j = 0; j < 4; ++j)
            bF[j] = *reinterpret_cast<const short8*>(&Bs[(wn * 64 + j * 16 + m16) * 32 + quad * 8]);
#pragma unroll
        for (int i = 0; i < 4; ++i)
#pragma unroll
            for (int j = 0; j < 4; ++j)
                acc[i][j] = __builtin_amdgcn_mfma_f32_16x16x32_bf16(aF[i], bF[j], acc[i][j], 0, 0, 0);
    }

#pragma unroll
    for (int i = 0; i < 4; ++i)
#pragma unroll
        for (int j = 0; j < 4; ++j) {
            const int col = n0 + wn * 64 + j * 16 + m16;
#pragma unroll
            for (int rr = 0; rr < 4; ++rr) {
                const int row = m0 + wm * 64 + i * 16 + quad * 4 + rr;
                float v = acc[i][j][rr];
                Cout[(size_t)row * 1024 + col] = 0.5f * v * (1.0f + erff(v * 0.70710678118654752f));
            }
        }
}

// ---------------------------------------------------------------------------
extern "C" void kernel_launch(void* const* d_in, const int* in_sizes, int n_in,
                              void* d_out, int out_size, void* d_ws, size_t ws_size,
                              hipStream_t stream) {
    const float* x    = (const float*)d_in[0];  // [49152][1024] fp32
    const float* fc1w = (const float*)d_in[1];  // [4096][1024]  fp32
    const float* fc2w = (const float*)d_in[2];  // [1024][4096]  fp32
    const float* fc2b = (const float*)d_in[3];  // [1024]        fp32
    const float* mask = (const float*)d_in[4];  // [1024][1024]  fp32, s-major

    char* ws = (char*)d_ws;
    ushort* fc1T  = (ushort*)ws;                  //  8 MiB [1024 s][4096 d] bf16
    ushort* fc2wb = (ushort*)(ws + (8u  << 20));  //  8 MiB [1024 t][4096 d] bf16
    ushort* attnT = (ushort*)(ws + (16u << 20));  //  2 MiB [1024 t][1024 s] bf16
    float*  attnP = (float*)(ws + (18u << 20));   // 16 MiB 4x[1024][1024] fp32 (reused by xb)
    ushort* xb    = (ushort*)(ws + (18u << 20));  // 96 MiB [49152][1024] bf16
    const size_t XB_BYTES = 50331648ull * 2;
    const bool has_xb = ws_size >= (size_t)(18u << 20) + XB_BYTES;
    const bool has_p  = ws_size >= (size_t)(34u << 20);

    // weight prep (small)
    k_transpose<<<dim3(16, 64), 256, 0, stream>>>(fc1w, fc1T);
    k_cvt<<<2048, 256, 0, stream>>>(fc2w, fc2wb, 524288);

    // attn: K-split x4 (1024 wg = 4 blocks/CU; was 256 wg = pure latency) then
    // combine. attnP region is reused by xb AFTER k_attn_fin completes.
    if (has_p) {
        k_gemm_b<64, 64, 2, 1><<<dim3(16, 16, 4), 256, 0, stream>>>(
            fc1T, fc2wb, nullptr, nullptr, attnP, 4096, 4096, 32);
        k_attn_fin<<<512, 256, 0, stream>>>(attnP, fc2b, mask, attnT);
    } else {
        k_gemm_b<64, 64, 0, 1><<<dim3(16, 16), 256, 0, stream>>>(
            fc1T, fc2wb, fc2b, mask, attnT, 4096, 4096, 128);
    }

    // main: out[m][t] = gelu(x·attnT^T), fp32 store
    if (has_xb) {
        k_cvt<<<24576, 256, 0, stream>>>(x, xb, 6291456);
        k_gemm8<<<dim3(4, 192), 512, 0, stream>>>(xb, attnT, (float*)d_out);
    } else {
        k_gemm_f32a<<<dim3(8, 384), 256, 0, stream>>>(x, attnT, (float*)d_out, 1024, 1024, 32);
    }
}